// Round 1
// baseline (588.246 us; speedup 1.0000x reference)
//
#include <hip/hip_runtime.h>

// Problem constants (match reference)
constexpr int N_  = 10000;   // nodes
constexpr int E_  = 100000;  // edges per direction
constexpr int HC_ = 512;     // H*C
constexpr float NEG_SLOPE_ = 0.2f;

// ============================ CSR build ============================

__global__ void k_hist(const int* __restrict__ fdst, const int* __restrict__ bdst,
                       int* __restrict__ degf, int* __restrict__ degb) {
  int e = blockIdx.x * 256 + threadIdx.x;
  if (e < E_) {
    atomicAdd(&degf[fdst[e]], 1);
    atomicAdd(&degb[bdst[e]], 1);
  }
}

__global__ void k_scan(const int* __restrict__ degf, const int* __restrict__ degb,
                       int* __restrict__ rpf, int* __restrict__ rpb) {
  const int* deg = blockIdx.x ? degb : degf;
  int* rp = blockIdx.x ? rpb : rpf;
  const int CH = 40;  // 256*40 = 10240 >= N_
  int t = threadIdx.x;
  int base = t * CH;
  int s = 0;
  for (int i = 0; i < CH; ++i) {
    int idx = base + i;
    if (idx < N_) s += deg[idx];
  }
  __shared__ int lds[256];
  lds[t] = s;
  __syncthreads();
  for (int off = 1; off < 256; off <<= 1) {
    int v = (t >= off) ? lds[t - off] : 0;
    __syncthreads();
    lds[t] += v;
    __syncthreads();
  }
  int run = lds[t] - s;  // exclusive prefix
  for (int i = 0; i < CH; ++i) {
    int idx = base + i;
    if (idx < N_) { rp[idx] = run; run += deg[idx]; }
  }
  if (t == 255) rp[N_] = lds[255];
}

__global__ void k_scatter(const int* __restrict__ src, const int* __restrict__ dst,
                          const int* __restrict__ rp, int* __restrict__ cur,
                          int* __restrict__ csrc, int* __restrict__ ceid) {
  int e = blockIdx.x * 256 + threadIdx.x;
  if (e < E_) {
    int d = dst[e];
    int pos = rp[d] + atomicAdd(&cur[d], 1);
    csrc[pos] = src[e];
    ceid[pos] = e;
  }
}

// ============================ weight concat ============================
// WCAT[l][k][j], j in [0,2048): [Wl_f | Wr_f | Wl_b | Wr_b]

__global__ void k_wcat(const float* __restrict__ Wl_f, const float* __restrict__ Wr_f,
                       const float* __restrict__ Wl_b, const float* __restrict__ Wr_b,
                       const float* __restrict__ bl_f, const float* __restrict__ br_f,
                       const float* __restrict__ bl_b, const float* __restrict__ br_b,
                       float* __restrict__ WCAT, float* __restrict__ BCAT) {
  int idx = blockIdx.x * 256 + threadIdx.x;
  if (idx < 2 * 128 * 2048) {
    int l = idx / (128 * 2048);
    int rem = idx - l * 128 * 2048;
    int k = rem >> 11;
    int j = rem & 2047;
    int grp = j >> 9, jj = j & 511;
    const float* W = grp == 0 ? Wl_f : grp == 1 ? Wr_f : grp == 2 ? Wl_b : Wr_b;
    WCAT[idx] = W[((size_t)l * 128 + k) * 512 + jj];
  }
  if (idx < 2 * 2048) {
    int l = idx >> 11, j = idx & 2047;
    int grp = j >> 9, jj = j & 511;
    const float* bs = grp == 0 ? bl_f : grp == 1 ? br_f : grp == 2 ? bl_b : br_b;
    BCAT[idx] = bs[l * 512 + jj];
  }
}

// ============================ fp32 GEMM ============================
// C[M,Ncols] = A[M,K] @ B[K,Ncols] + bias, optional ReLU.
// 64x64 tile, 4x4 micro-tile, Kc=32, LDS staged (A transposed in LDS).

template <int K, bool RELU>
__global__ __launch_bounds__(256) void k_gemm(const float* __restrict__ A,
                                              const float* __restrict__ B,
                                              const float* __restrict__ bias,
                                              float* __restrict__ C, int M, int Ncols) {
  __shared__ __align__(16) float As[32][68];  // [k][m]
  __shared__ __align__(16) float Bs[32][68];  // [k][n]
  int tid = threadIdx.x;
  int tx = tid & 15, ty = tid >> 4;
  int col0 = blockIdx.x * 64, row0 = blockIdx.y * 64;
  float acc[4][4] = {};
  for (int kc = 0; kc < K; kc += 32) {
#pragma unroll
    for (int i = 0; i < 2; ++i) {
      int f = tid * 2 + i;          // 512 float4s total
      int m = f >> 3;               // row in tile
      int kq = (f & 7) << 2;        // k offset
      int row = row0 + m;
      float4 v = make_float4(0.f, 0.f, 0.f, 0.f);
      if (row < M) v = *reinterpret_cast<const float4*>(A + (size_t)row * K + kc + kq);
      As[kq + 0][m] = v.x;
      As[kq + 1][m] = v.y;
      As[kq + 2][m] = v.z;
      As[kq + 3][m] = v.w;
    }
#pragma unroll
    for (int i = 0; i < 2; ++i) {
      int f = tid * 2 + i;
      int k = f >> 4;
      int nq = (f & 15) << 2;
      *reinterpret_cast<float4*>(&Bs[k][nq]) =
          *reinterpret_cast<const float4*>(B + (size_t)(kc + k) * Ncols + col0 + nq);
    }
    __syncthreads();
#pragma unroll
    for (int k = 0; k < 32; ++k) {
      float4 a4 = *reinterpret_cast<const float4*>(&As[k][ty * 4]);
      float4 b4 = *reinterpret_cast<const float4*>(&Bs[k][tx * 4]);
      float a[4] = {a4.x, a4.y, a4.z, a4.w};
      float b[4] = {b4.x, b4.y, b4.z, b4.w};
#pragma unroll
      for (int ii = 0; ii < 4; ++ii)
#pragma unroll
        for (int jj = 0; jj < 4; ++jj) acc[ii][jj] = fmaf(a[ii], b[jj], acc[ii][jj]);
    }
    __syncthreads();
  }
  float4 bb = *reinterpret_cast<const float4*>(bias + col0 + tx * 4);
#pragma unroll
  for (int i = 0; i < 4; ++i) {
    int row = row0 + ty * 4 + i;
    if (row < M) {
      float4 o;
      o.x = acc[i][0] + bb.x;
      o.y = acc[i][1] + bb.y;
      o.z = acc[i][2] + bb.z;
      o.w = acc[i][3] + bb.w;
      if (RELU) {
        o.x = fmaxf(o.x, 0.f); o.y = fmaxf(o.y, 0.f);
        o.z = fmaxf(o.z, 0.f); o.w = fmaxf(o.w, 0.f);
      }
      *reinterpret_cast<float4*>(C + (size_t)row * Ncols + col0 + tx * 4) = o;
    }
  }
}

// ============================ GATv2 aggregation ============================
// Node-centric: block = one (node, dir). 128 threads, 4 channels each.
// Threads [0,32)=head0, [32,64)=head1, [64,96)=head2, [96,128)=head3
// (heads align with 32-lane groups -> shuffle reduction for the att-dot).
// Accumulates sum(ex * xl[src]) and sum(ex) -> divide at end (== softmax agg).

__global__ __launch_bounds__(128) void k_gat(
    const float* __restrict__ XLXR, const float* __restrict__ eattr,
    const int* __restrict__ rpf, const int* __restrict__ csf, const int* __restrict__ cef,
    const int* __restrict__ rpb, const int* __restrict__ csb, const int* __restrict__ ceb,
    const float* __restrict__ We_f, const float* __restrict__ We_b,
    const float* __restrict__ att_f, const float* __restrict__ att_b,
    const float* __restrict__ bias_f, const float* __restrict__ bias_b,
    float* __restrict__ FB, int layer) {
  const int n = blockIdx.x;
  const int dir = blockIdx.y;
  const int* rp = dir ? rpb : rpf;
  const int* cs = dir ? csb : csf;
  const int* ce = dir ? ceb : cef;
  const float* We = (dir ? We_b : We_f) + layer * 16 * HC_;
  const float* att = (dir ? att_b : att_f) + layer * HC_;
  const float* bias = (dir ? bias_b : bias_f) + layer * 128;
  const int t = threadIdx.x;
  const int ch = t << 2;
  const float* XL = XLXR + dir * 1024;  // cols [dir*1024, dir*1024+512) of (N,2048)
  const float* XR = XL + 512;

  float4 a4 = *reinterpret_cast<const float4*>(att + ch);
  float4 xr4 = *reinterpret_cast<const float4*>(XR + (size_t)n * 2048 + ch);
  float4 we[16];
#pragma unroll
  for (int k = 0; k < 16; ++k)
    we[k] = *reinterpret_cast<const float4*>(We + k * HC_ + ch);

  float accx = 0.f, accy = 0.f, accz = 0.f, accw = 0.f;
  float denom = 0.f;
  const int s = rp[n], epos = rp[n + 1];
  for (int i = s; i < epos; ++i) {
    const int sn = cs[i];
    const int eid = ce[i];
    float4 xl4 = *reinterpret_cast<const float4*>(XL + (size_t)sn * 2048 + ch);
    const float4* eap = reinterpret_cast<const float4*>(eattr + (size_t)eid * 16);
    float4 e0 = eap[0], e1 = eap[1], e2 = eap[2], e3 = eap[3];
    float zx = xl4.x + xr4.x;
    float zy = xl4.y + xr4.y;
    float zz = xl4.z + xr4.z;
    float zw = xl4.w + xr4.w;
#define EE_(c, kk)                  \
  zx = fmaf(c, we[kk].x, zx);       \
  zy = fmaf(c, we[kk].y, zy);       \
  zz = fmaf(c, we[kk].z, zz);       \
  zw = fmaf(c, we[kk].w, zw)
    EE_(e0.x, 0); EE_(e0.y, 1); EE_(e0.z, 2); EE_(e0.w, 3);
    EE_(e1.x, 4); EE_(e1.y, 5); EE_(e1.z, 6); EE_(e1.w, 7);
    EE_(e2.x, 8); EE_(e2.y, 9); EE_(e2.z, 10); EE_(e2.w, 11);
    EE_(e3.x, 12); EE_(e3.y, 13); EE_(e3.z, 14); EE_(e3.w, 15);
#undef EE_
    float lx = zx > 0.f ? zx : NEG_SLOPE_ * zx;
    float ly = zy > 0.f ? zy : NEG_SLOPE_ * zy;
    float lz = zz > 0.f ? zz : NEG_SLOPE_ * zz;
    float lw = zw > 0.f ? zw : NEG_SLOPE_ * zw;
    float part = fmaf(lx, a4.x, fmaf(ly, a4.y, fmaf(lz, a4.z, lw * a4.w)));
    // per-head (32-lane group) reduction; all lanes receive the sum
    part += __shfl_xor(part, 1, 32);
    part += __shfl_xor(part, 2, 32);
    part += __shfl_xor(part, 4, 32);
    part += __shfl_xor(part, 8, 32);
    part += __shfl_xor(part, 16, 32);
    float ex = __expf(part);  // logits are O(+-3): no max-subtraction needed
    denom += ex;
    accx = fmaf(ex, xl4.x, accx);
    accy = fmaf(ex, xl4.y, accy);
    accz = fmaf(ex, xl4.z, accz);
    accw = fmaf(ex, xl4.w, accw);
  }
  __shared__ __align__(16) float red[512];
  float inv = denom > 0.f ? 1.f / denom : 0.f;  // deg==0 -> out = bias
  red[ch] = accx * inv;
  red[ch + 1] = accy * inv;
  red[ch + 2] = accz * inv;
  red[ch + 3] = accw * inv;
  __syncthreads();
  if (t < 32) {  // head mean + bias, write f/b half of FB row
    int c = t << 2;
    float4 r0 = *reinterpret_cast<const float4*>(&red[c]);
    float4 r1 = *reinterpret_cast<const float4*>(&red[c + 128]);
    float4 r2 = *reinterpret_cast<const float4*>(&red[c + 256]);
    float4 r3 = *reinterpret_cast<const float4*>(&red[c + 384]);
    float4 b4 = *reinterpret_cast<const float4*>(bias + c);
    float4 o;
    o.x = 0.25f * (r0.x + r1.x + r2.x + r3.x) + b4.x;
    o.y = 0.25f * (r0.y + r1.y + r2.y + r3.y) + b4.y;
    o.z = 0.25f * (r0.z + r1.z + r2.z + r3.z) + b4.z;
    o.w = 0.25f * (r0.w + r1.w + r2.w + r3.w) + b4.w;
    *reinterpret_cast<float4*>(FB + (size_t)n * 256 + dir * 128 + c) = o;
  }
}

// ============================ BatchNorm ============================

__global__ __launch_bounds__(256) void k_stats(const float* __restrict__ m2,
                                               float* __restrict__ stats) {
  int t = threadIdx.x;
  int col = t & 127;
  int rl = t >> 7;
  float s1 = 0.f, s2 = 0.f;
  for (int r = blockIdx.x * 2 + rl; r < N_; r += gridDim.x * 2) {
    float v = m2[(size_t)r * 128 + col];
    s1 += v;
    s2 = fmaf(v, v, s2);
  }
  __shared__ float l1[256], l2[256];
  l1[t] = s1;
  l2[t] = s2;
  __syncthreads();
  if (rl == 0) {
    s1 += l1[t + 128];
    s2 += l2[t + 128];
    atomicAdd(&stats[col], s1);
    atomicAdd(&stats[128 + col], s2);
  }
}

__global__ void k_bn(const float* __restrict__ m2, const float* __restrict__ stats,
                     const float* __restrict__ gamma, const float* __restrict__ beta,
                     float* __restrict__ out) {
  int idx = blockIdx.x * 256 + threadIdx.x;
  if (idx >= N_ * 32) return;
  int n = idx >> 5;
  int c = (idx & 31) << 2;
  float4 v = *reinterpret_cast<const float4*>(m2 + (size_t)n * 128 + c);
  const float invN = 1.f / (float)N_;
  float4 o;
  {
    float mu = stats[c + 0] * invN;
    float var = stats[128 + c + 0] * invN - mu * mu;
    float rs = rsqrtf(var + 1e-5f);
    o.x = fmaxf(gamma[c + 0] * (v.x - mu) * rs + beta[c + 0], 0.f);
  }
  {
    float mu = stats[c + 1] * invN;
    float var = stats[128 + c + 1] * invN - mu * mu;
    float rs = rsqrtf(var + 1e-5f);
    o.y = fmaxf(gamma[c + 1] * (v.y - mu) * rs + beta[c + 1], 0.f);
  }
  {
    float mu = stats[c + 2] * invN;
    float var = stats[128 + c + 2] * invN - mu * mu;
    float rs = rsqrtf(var + 1e-5f);
    o.z = fmaxf(gamma[c + 2] * (v.z - mu) * rs + beta[c + 2], 0.f);
  }
  {
    float mu = stats[c + 3] * invN;
    float var = stats[128 + c + 3] * invN - mu * mu;
    float rs = rsqrtf(var + 1e-5f);
    o.w = fmaxf(gamma[c + 3] * (v.w - mu) * rs + beta[c + 3], 0.f);
  }
  *reinterpret_cast<float4*>(out + (size_t)n * 128 + c) = o;
}

// ============================ launch ============================

extern "C" void kernel_launch(void* const* d_in, const int* in_sizes, int n_in,
                              void* d_out, int out_size, void* d_ws, size_t ws_size,
                              hipStream_t stream) {
  (void)in_sizes; (void)n_in; (void)out_size; (void)ws_size;
  const float* x      = (const float*)d_in[0];
  const int*   fwd    = (const int*)d_in[1];
  const int*   bwd    = (const int*)d_in[2];
  const float* eattr  = (const float*)d_in[3];
  const float* Wl_f   = (const float*)d_in[4];
  const float* bl_f   = (const float*)d_in[5];
  const float* Wr_f   = (const float*)d_in[6];
  const float* br_f   = (const float*)d_in[7];
  const float* We_f   = (const float*)d_in[8];
  const float* att_f  = (const float*)d_in[9];
  const float* bias_f = (const float*)d_in[10];
  const float* Wl_b   = (const float*)d_in[11];
  const float* bl_b   = (const float*)d_in[12];
  const float* Wr_b   = (const float*)d_in[13];
  const float* br_b   = (const float*)d_in[14];
  const float* We_b   = (const float*)d_in[15];
  const float* att_b  = (const float*)d_in[16];
  const float* bias_b = (const float*)d_in[17];
  const float* Wm1    = (const float*)d_in[18];
  const float* bm1    = (const float*)d_in[19];
  const float* Wm2    = (const float*)d_in[20];
  const float* bm2    = (const float*)d_in[21];
  const float* gamma  = (const float*)d_in[22];
  const float* beta   = (const float*)d_in[23];

  char* ws = (char*)d_ws;
  size_t off = 0;
  auto take = [&](size_t bytes) -> char* {
    char* p = ws + off;
    off += (bytes + 255) & ~(size_t)255;
    return p;
  };
  float* WCAT = (float*)take(2ull * 128 * 2048 * 4);
  float* BCAT = (float*)take(2ull * 2048 * 4);
  float* XLXR = (float*)take((size_t)N_ * 2048 * 4);
  float* FB   = (float*)take((size_t)N_ * 256 * 4);
  float* M1   = (float*)take((size_t)N_ * 128 * 4);
  float* M2   = (float*)take((size_t)N_ * 128 * 4);
  float* HBUF = (float*)take((size_t)N_ * 128 * 4);
  int* DEGS   = (int*)take(4ull * 40192);  // deg_f | deg_b | cur_f | cur_b
  int* degf = DEGS;
  int* degb = DEGS + (40192 / 4);
  int* curf = DEGS + 2 * (40192 / 4);
  int* curb = DEGS + 3 * (40192 / 4);
  int* rpf = (int*)take((N_ + 1) * 4);
  int* rpb = (int*)take((N_ + 1) * 4);
  int* csf = (int*)take((size_t)E_ * 4);
  int* cef = (int*)take((size_t)E_ * 4);
  int* csb = (int*)take((size_t)E_ * 4);
  int* ceb = (int*)take((size_t)E_ * 4);
  float* STATS = (float*)take(256 * 4);

  // CSR build (edge structure is launch-constant; rebuilt every call)
  hipMemsetAsync(DEGS, 0, 4ull * 40192, stream);
  k_wcat<<<2048, 256, 0, stream>>>(Wl_f, Wr_f, Wl_b, Wr_b, bl_f, br_f, bl_b, br_b, WCAT, BCAT);
  k_hist<<<(E_ + 255) / 256, 256, 0, stream>>>(fwd + E_, bwd + E_, degf, degb);
  k_scan<<<2, 256, 0, stream>>>(degf, degb, rpf, rpb);
  k_scatter<<<(E_ + 255) / 256, 256, 0, stream>>>(fwd, fwd + E_, rpf, curf, csf, cef);
  k_scatter<<<(E_ + 255) / 256, 256, 0, stream>>>(bwd, bwd + E_, rpb, curb, csb, ceb);

  for (int l = 0; l < 2; ++l) {
    const float* hin = (l == 0) ? x : HBUF;
    // XLXR = hin @ [Wl_f|Wr_f|Wl_b|Wr_b] + biases   (N,2048)
    k_gemm<128, false><<<dim3(2048 / 64, (N_ + 63) / 64), 256, 0, stream>>>(
        hin, WCAT + (size_t)l * 128 * 2048, BCAT + l * 2048, XLXR, N_, 2048);
    // GAT aggregation, both directions -> FB (N,256) = [f | b]
    k_gat<<<dim3(N_, 2), 128, 0, stream>>>(XLXR, eattr, rpf, csf, cef, rpb, csb, ceb,
                                           We_f, We_b, att_f, att_b, bias_f, bias_b, FB, l);
    // merge MLP
    k_gemm<256, true><<<dim3(128 / 64, (N_ + 63) / 64), 256, 0, stream>>>(
        FB, Wm1 + (size_t)l * 256 * 128, bm1 + l * 128, M1, N_, 128);
    k_gemm<128, false><<<dim3(128 / 64, (N_ + 63) / 64), 256, 0, stream>>>(
        M1, Wm2 + (size_t)l * 128 * 128, bm2 + l * 128, M2, N_, 128);
    // BatchNorm (training stats) + ReLU
    hipMemsetAsync(STATS, 0, 256 * 4, stream);
    k_stats<<<64, 256, 0, stream>>>(M2, STATS);
    float* hout = (l == 1) ? (float*)d_out : HBUF;
    k_bn<<<(N_ * 32 + 255) / 256, 256, 0, stream>>>(M2, STATS, gamma + l * 128,
                                                    beta + l * 128, hout);
  }
}

// Round 2
// 489.010 us; speedup vs baseline: 1.2029x; 1.2029x over previous
//
#include <hip/hip_runtime.h>

// Problem constants (match reference)
constexpr int N_  = 10000;   // nodes
constexpr int E_  = 100000;  // edges per direction
constexpr int HC_ = 512;     // H*C
constexpr int MP_ = 10112;   // N padded to multiple of 128 (79*128)
constexpr float NEG_SLOPE_ = 0.2f;

typedef unsigned int u32;
typedef unsigned short u16;
typedef __attribute__((ext_vector_type(8))) short bf16x8;
typedef __attribute__((ext_vector_type(4))) float f32x4;

__device__ __forceinline__ u16 f2bf(float f) {  // RNE
  u32 u = __float_as_uint(f);
  u32 r = u + 0x7fffu + ((u >> 16) & 1u);
  return (u16)(r >> 16);
}
__device__ __forceinline__ float bf2f(u16 u) {
  return __uint_as_float((u32)u << 16);
}
__device__ __forceinline__ void async16(const void* g, void* l) {
  // global -> LDS DMA, 16 B/lane; LDS dest = wave-uniform base + lane*16
  __builtin_amdgcn_global_load_lds((const __attribute__((address_space(1))) u32*)g,
                                   (__attribute__((address_space(3))) u32*)l, 16, 0, 0);
}

// ============================ CSR build ============================

__global__ void k_hist(const int* __restrict__ fdst, const int* __restrict__ bdst,
                       int* __restrict__ degf, int* __restrict__ degb) {
  int e = blockIdx.x * 256 + threadIdx.x;
  if (e < E_) {
    atomicAdd(&degf[fdst[e]], 1);
    atomicAdd(&degb[bdst[e]], 1);
  }
}

__global__ void k_scan(const int* __restrict__ degf, const int* __restrict__ degb,
                       int* __restrict__ rpf, int* __restrict__ rpb) {
  const int* deg = blockIdx.x ? degb : degf;
  int* rp = blockIdx.x ? rpb : rpf;
  const int CH = 40;
  int t = threadIdx.x;
  int base = t * CH;
  int s = 0;
  for (int i = 0; i < CH; ++i) {
    int idx = base + i;
    if (idx < N_) s += deg[idx];
  }
  __shared__ int lds[256];
  lds[t] = s;
  __syncthreads();
  for (int off = 1; off < 256; off <<= 1) {
    int v = (t >= off) ? lds[t - off] : 0;
    __syncthreads();
    lds[t] += v;
    __syncthreads();
  }
  int run = lds[t] - s;
  for (int i = 0; i < CH; ++i) {
    int idx = base + i;
    if (idx < N_) { rp[idx] = run; run += deg[idx]; }
  }
  if (t == 255) rp[N_] = lds[255];
}

__global__ void k_scatter(const int* __restrict__ src, const int* __restrict__ dst,
                          const int* __restrict__ rp, int* __restrict__ cur,
                          int* __restrict__ csrc, int* __restrict__ ceid) {
  int e = blockIdx.x * 256 + threadIdx.x;
  if (e < E_) {
    int d = dst[e];
    int pos = rp[d] + atomicAdd(&cur[d], 1);
    csrc[pos] = src[e];
    ceid[pos] = e;
  }
}

// ============================ param prep ============================
// WCATh[l][j][k] (bf16, j in [0,2048) = [Wl_f|Wr_f|Wl_b|Wr_b] cols, TRANSPOSED k-contig)
// BCAT [l][2048] fp32; WM1h[l][n][k] k<256; WM2h[l][n][k] k<128 (both transposed bf16)

__global__ void k_wprep(const float* __restrict__ Wl_f, const float* __restrict__ Wr_f,
                        const float* __restrict__ Wl_b, const float* __restrict__ Wr_b,
                        const float* __restrict__ bl_f, const float* __restrict__ br_f,
                        const float* __restrict__ bl_b, const float* __restrict__ br_b,
                        const float* __restrict__ Wm1, const float* __restrict__ Wm2,
                        u16* __restrict__ WCATh, float* __restrict__ BCAT,
                        u16* __restrict__ WM1h, u16* __restrict__ WM2h) {
  int idx = blockIdx.x * 256 + threadIdx.x;
  if (idx < 2 * 2048 * 128) {
    int l = idx >> 18;
    int rem = idx & 262143;
    int j = rem >> 7, k = rem & 127;
    int grp = j >> 9, jj = j & 511;
    const float* W = grp == 0 ? Wl_f : grp == 1 ? Wr_f : grp == 2 ? Wl_b : Wr_b;
    WCATh[idx] = f2bf(W[((size_t)(l * 128 + k)) * 512 + jj]);
  }
  if (idx < 2 * 2048) {
    int l = idx >> 11, j = idx & 2047;
    int grp = j >> 9, jj = j & 511;
    const float* bs = grp == 0 ? bl_f : grp == 1 ? br_f : grp == 2 ? bl_b : br_b;
    BCAT[idx] = bs[l * 512 + jj];
  }
  if (idx < 2 * 128 * 256) {  // WM1h[(l*128+n)*256+k] = Wm1[(l*256+k)*128+n]
    int l = idx >> 15;
    int rem = idx & 32767;
    int n = rem >> 8, k = rem & 255;
    WM1h[idx] = f2bf(Wm1[((size_t)(l * 256 + k)) * 128 + n]);
  }
  if (idx < 2 * 128 * 128) {  // WM2h[(l*128+n)*128+k] = Wm2[(l*128+k)*128+n]
    int l = idx >> 14;
    int rem = idx & 16383;
    int n = rem >> 7, k = rem & 127;
    WM2h[idx] = f2bf(Wm2[((size_t)(l * 128 + k)) * 128 + n]);
  }
}

__global__ void k_cast(const float* __restrict__ x, u16* __restrict__ Xh) {
  int idx = blockIdx.x * 256 + threadIdx.x;  // one thread per 4 elems
  if (idx >= MP_ * 32) return;
  int row = idx >> 5;
  int c4 = (idx & 31) << 2;
  ushort4 o;
  if (row < N_) {
    float4 v = *reinterpret_cast<const float4*>(x + (size_t)row * 128 + c4);
    o.x = f2bf(v.x); o.y = f2bf(v.y); o.z = f2bf(v.z); o.w = f2bf(v.w);
  } else {
    o.x = o.y = o.z = o.w = 0;
  }
  *reinterpret_cast<ushort4*>(Xh + (size_t)row * 128 + c4) = o;
}

// ============================ bf16 MFMA GEMM ============================
// C[M, Ncols] = A[Mpad, K](bf16) @ Bt[Ncols, K]^T(bf16) + bias(fp32)
// 128x128 tile, 4 waves (64x64 quadrant each), BK=128 chunks, global_load_lds staging.

template <int K, bool RELU, bool BF16OUT>
__global__ __launch_bounds__(256) void k_hgemm(const u16* __restrict__ A,
                                               const u16* __restrict__ Bt,
                                               const float* __restrict__ bias,
                                               u16* __restrict__ Cb, float* __restrict__ Cf,
                                               int M, int Ncols) {
  __shared__ __align__(16) u16 As[128 * 128];  // [m][k-chunk]
  __shared__ __align__(16) u16 Bs[128 * 128];  // [n][k-chunk]
  const int tid = threadIdx.x;
  const int lane = tid & 63, wave = tid >> 6;
  const int l16 = lane & 15, lq = lane >> 4;
  const int wm = wave & 1, wn = wave >> 1;
  const u16* Arow0 = A + (size_t)blockIdx.y * 128 * K;
  const u16* Brow0 = Bt + (size_t)blockIdx.x * 128 * K;

  f32x4 acc[4][4];
#pragma unroll
  for (int i = 0; i < 4; ++i)
#pragma unroll
    for (int j = 0; j < 4; ++j) acc[i][j] = (f32x4){0.f, 0.f, 0.f, 0.f};

  for (int kc = 0; kc < K; kc += 128) {
    if (kc) __syncthreads();
    // stage 128x128 bf16 A-tile and B-tile: 32 KB each; 1 instr = 64 lanes x 16 B = 4 rows
#pragma unroll
    for (int i = 0; i < 8; ++i) {
      int rg = i * 4 + wave;                 // row-group (4 rows)
      int r = rg * 4 + (lane >> 4);          // row 0..127
      int cc = kc + (lane & 15) * 8;         // k element offset (16 B piece)
      async16(Arow0 + (size_t)r * K + cc, (char*)As + rg * 1024);
      async16(Brow0 + (size_t)r * K + cc, (char*)Bs + rg * 1024);
    }
    __syncthreads();
    const u16* Ab = As + (wm * 64 + l16) * 128 + lq * 8;
    const u16* Bb = Bs + (wn * 64 + l16) * 128 + lq * 8;
#pragma unroll
    for (int ks = 0; ks < 4; ++ks) {
      bf16x8 af[4], bfr[4];
#pragma unroll
      for (int i = 0; i < 4; ++i)
        af[i] = *reinterpret_cast<const bf16x8*>(Ab + i * 16 * 128 + ks * 32);
#pragma unroll
      for (int j = 0; j < 4; ++j)
        bfr[j] = *reinterpret_cast<const bf16x8*>(Bb + j * 16 * 128 + ks * 32);
#pragma unroll
      for (int i = 0; i < 4; ++i)
#pragma unroll
        for (int j = 0; j < 4; ++j)
          acc[i][j] = __builtin_amdgcn_mfma_f32_16x16x32_bf16(af[i], bfr[j], acc[i][j], 0, 0, 0);
    }
  }

  const int row_base = blockIdx.y * 128 + wm * 64;
  const int col_base = blockIdx.x * 128 + wn * 64;
#pragma unroll
  for (int i = 0; i < 4; ++i) {
#pragma unroll
    for (int r = 0; r < 4; ++r) {
      int row = row_base + i * 16 + lq * 4 + r;
      if (row < M) {
#pragma unroll
        for (int j = 0; j < 4; ++j) {
          int col = col_base + j * 16 + l16;
          float v = acc[i][j][r] + bias[col];
          if (RELU) v = fmaxf(v, 0.f);
          if (BF16OUT) Cb[(size_t)row * Ncols + col] = f2bf(v);
          else Cf[(size_t)row * Ncols + col] = v;
        }
      }
    }
  }
}

// ============================ GATv2 aggregation ============================
// Block = one (node, dir). 128 threads, 4 channels each; heads = 32-lane groups.
// XLXRh is bf16 [N][2048]; accumulate unnormalized sum(ex*xl), sum(ex); FBh bf16 out.

__global__ __launch_bounds__(128) void k_gat(
    const u16* __restrict__ XLXRh, const float* __restrict__ eattr,
    const int* __restrict__ rpf, const int* __restrict__ csf, const int* __restrict__ cef,
    const int* __restrict__ rpb, const int* __restrict__ csb, const int* __restrict__ ceb,
    const float* __restrict__ We_f, const float* __restrict__ We_b,
    const float* __restrict__ att_f, const float* __restrict__ att_b,
    const float* __restrict__ bias_f, const float* __restrict__ bias_b,
    u16* __restrict__ FBh, int layer) {
  const int n = blockIdx.x;
  const int dir = blockIdx.y;
  const int* rp = dir ? rpb : rpf;
  const int* cs = dir ? csb : csf;
  const int* ce = dir ? ceb : cef;
  const float* We = (dir ? We_b : We_f) + layer * 16 * HC_;
  const float* att = (dir ? att_b : att_f) + layer * HC_;
  const float* bias = (dir ? bias_b : bias_f) + layer * 128;
  const int t = threadIdx.x;
  const int ch = t << 2;
  const u16* XL = XLXRh + dir * 1024;  // cols [dir*1024, +512)
  const u16* XR = XL + 512;

  float4 a4 = *reinterpret_cast<const float4*>(att + ch);
  ushort4 xru = *reinterpret_cast<const ushort4*>(XR + (size_t)n * 2048 + ch);
  float xrx = bf2f(xru.x), xry = bf2f(xru.y), xrz = bf2f(xru.z), xrw = bf2f(xru.w);
  float4 we[16];
#pragma unroll
  for (int k = 0; k < 16; ++k)
    we[k] = *reinterpret_cast<const float4*>(We + k * HC_ + ch);

  float accx = 0.f, accy = 0.f, accz = 0.f, accw = 0.f;
  float denom = 0.f;
  const int s = rp[n], epos = rp[n + 1];
  for (int i = s; i < epos; ++i) {
    const int sn = cs[i];
    const int eid = ce[i];
    ushort4 xlu = *reinterpret_cast<const ushort4*>(XL + (size_t)sn * 2048 + ch);
    float xlx = bf2f(xlu.x), xly = bf2f(xlu.y), xlz = bf2f(xlu.z), xlw = bf2f(xlu.w);
    const float4* eap = reinterpret_cast<const float4*>(eattr + (size_t)eid * 16);
    float4 e0 = eap[0], e1 = eap[1], e2 = eap[2], e3 = eap[3];
    float zx = xlx + xrx;
    float zy = xly + xry;
    float zz = xlz + xrz;
    float zw = xlw + xrw;
#define EE_(c, kk)                  \
  zx = fmaf(c, we[kk].x, zx);       \
  zy = fmaf(c, we[kk].y, zy);       \
  zz = fmaf(c, we[kk].z, zz);       \
  zw = fmaf(c, we[kk].w, zw)
    EE_(e0.x, 0); EE_(e0.y, 1); EE_(e0.z, 2); EE_(e0.w, 3);
    EE_(e1.x, 4); EE_(e1.y, 5); EE_(e1.z, 6); EE_(e1.w, 7);
    EE_(e2.x, 8); EE_(e2.y, 9); EE_(e2.z, 10); EE_(e2.w, 11);
    EE_(e3.x, 12); EE_(e3.y, 13); EE_(e3.z, 14); EE_(e3.w, 15);
#undef EE_
    float lx = zx > 0.f ? zx : NEG_SLOPE_ * zx;
    float ly = zy > 0.f ? zy : NEG_SLOPE_ * zy;
    float lz = zz > 0.f ? zz : NEG_SLOPE_ * zz;
    float lw = zw > 0.f ? zw : NEG_SLOPE_ * zw;
    float part = fmaf(lx, a4.x, fmaf(ly, a4.y, fmaf(lz, a4.z, lw * a4.w)));
    part += __shfl_xor(part, 1, 32);
    part += __shfl_xor(part, 2, 32);
    part += __shfl_xor(part, 4, 32);
    part += __shfl_xor(part, 8, 32);
    part += __shfl_xor(part, 16, 32);
    float ex = __expf(part);  // logits O(+-3): no max-subtraction needed
    denom += ex;
    accx = fmaf(ex, xlx, accx);
    accy = fmaf(ex, xly, accy);
    accz = fmaf(ex, xlz, accz);
    accw = fmaf(ex, xlw, accw);
  }
  __shared__ __align__(16) float red[512];
  float inv = denom > 0.f ? 1.f / denom : 0.f;  // deg==0 -> out = bias
  red[ch] = accx * inv;
  red[ch + 1] = accy * inv;
  red[ch + 2] = accz * inv;
  red[ch + 3] = accw * inv;
  __syncthreads();
  if (t < 32) {  // head mean + bias -> bf16
    int c = t << 2;
    float4 r0 = *reinterpret_cast<const float4*>(&red[c]);
    float4 r1 = *reinterpret_cast<const float4*>(&red[c + 128]);
    float4 r2 = *reinterpret_cast<const float4*>(&red[c + 256]);
    float4 r3 = *reinterpret_cast<const float4*>(&red[c + 384]);
    float4 b4 = *reinterpret_cast<const float4*>(bias + c);
    ushort4 o;
    o.x = f2bf(0.25f * (r0.x + r1.x + r2.x + r3.x) + b4.x);
    o.y = f2bf(0.25f * (r0.y + r1.y + r2.y + r3.y) + b4.y);
    o.z = f2bf(0.25f * (r0.z + r1.z + r2.z + r3.z) + b4.z);
    o.w = f2bf(0.25f * (r0.w + r1.w + r2.w + r3.w) + b4.w);
    *reinterpret_cast<ushort4*>(FBh + (size_t)n * 256 + dir * 128 + c) = o;
  }
}

// ============================ BatchNorm ============================

__global__ __launch_bounds__(256) void k_stats(const float* __restrict__ m2,
                                               float* __restrict__ stats) {
  int t = threadIdx.x;
  int col = t & 127;
  int rl = t >> 7;
  float s1 = 0.f, s2 = 0.f;
  for (int r = blockIdx.x * 2 + rl; r < N_; r += gridDim.x * 2) {
    float v = m2[(size_t)r * 128 + col];
    s1 += v;
    s2 = fmaf(v, v, s2);
  }
  __shared__ float l1[256], l2[256];
  l1[t] = s1;
  l2[t] = s2;
  __syncthreads();
  if (rl == 0) {
    s1 += l1[t + 128];
    s2 += l2[t + 128];
    atomicAdd(&stats[col], s1);
    atomicAdd(&stats[128 + col], s2);
  }
}

__global__ void k_bn(const float* __restrict__ m2, const float* __restrict__ stats,
                     const float* __restrict__ gamma, const float* __restrict__ beta,
                     u16* __restrict__ houth, float* __restrict__ outf) {
  int idx = blockIdx.x * 256 + threadIdx.x;
  if (idx >= N_ * 32) return;
  int n = idx >> 5;
  int c = (idx & 31) << 2;
  float4 v = *reinterpret_cast<const float4*>(m2 + (size_t)n * 128 + c);
  const float invN = 1.f / (float)N_;
  float o[4];
  float vv[4] = {v.x, v.y, v.z, v.w};
#pragma unroll
  for (int q = 0; q < 4; ++q) {
    float mu = stats[c + q] * invN;
    float var = stats[128 + c + q] * invN - mu * mu;
    float rs = rsqrtf(var + 1e-5f);
    o[q] = fmaxf(gamma[c + q] * (vv[q] - mu) * rs + beta[c + q], 0.f);
  }
  ushort4 oh;
  oh.x = f2bf(o[0]); oh.y = f2bf(o[1]); oh.z = f2bf(o[2]); oh.w = f2bf(o[3]);
  *reinterpret_cast<ushort4*>(houth + (size_t)n * 128 + c) = oh;
  if (outf) {
    float4 of = make_float4(o[0], o[1], o[2], o[3]);
    *reinterpret_cast<float4*>(outf + (size_t)n * 128 + c) = of;
  }
}

// ============================ launch ============================

extern "C" void kernel_launch(void* const* d_in, const int* in_sizes, int n_in,
                              void* d_out, int out_size, void* d_ws, size_t ws_size,
                              hipStream_t stream) {
  (void)in_sizes; (void)n_in; (void)out_size; (void)ws_size;
  const float* x      = (const float*)d_in[0];
  const int*   fwd    = (const int*)d_in[1];
  const int*   bwd    = (const int*)d_in[2];
  const float* eattr  = (const float*)d_in[3];
  const float* Wl_f   = (const float*)d_in[4];
  const float* bl_f   = (const float*)d_in[5];
  const float* Wr_f   = (const float*)d_in[6];
  const float* br_f   = (const float*)d_in[7];
  const float* We_f   = (const float*)d_in[8];
  const float* att_f  = (const float*)d_in[9];
  const float* bias_f = (const float*)d_in[10];
  const float* Wl_b   = (const float*)d_in[11];
  const float* bl_b   = (const float*)d_in[12];
  const float* Wr_b   = (const float*)d_in[13];
  const float* br_b   = (const float*)d_in[14];
  const float* We_b   = (const float*)d_in[15];
  const float* att_b  = (const float*)d_in[16];
  const float* bias_b = (const float*)d_in[17];
  const float* Wm1    = (const float*)d_in[18];
  const float* bm1    = (const float*)d_in[19];
  const float* Wm2    = (const float*)d_in[20];
  const float* bm2    = (const float*)d_in[21];
  const float* gamma  = (const float*)d_in[22];
  const float* beta   = (const float*)d_in[23];

  char* ws = (char*)d_ws;
  size_t off = 0;
  auto take = [&](size_t bytes) -> char* {
    char* p = ws + off;
    off += (bytes + 255) & ~(size_t)255;
    return p;
  };
  u16* WCATh = (u16*)take(2ull * 2048 * 128 * 2);
  float* BCAT = (float*)take(2ull * 2048 * 4);
  u16* WM1h = (u16*)take(2ull * 128 * 256 * 2);
  u16* WM2h = (u16*)take(2ull * 128 * 128 * 2);
  u16* Xh    = (u16*)take((size_t)MP_ * 128 * 2);
  u16* HBh   = (u16*)take((size_t)MP_ * 128 * 2);
  u16* XLXRh = (u16*)take((size_t)MP_ * 2048 * 2);
  u16* FBh   = (u16*)take((size_t)MP_ * 256 * 2);
  u16* M1h   = (u16*)take((size_t)MP_ * 128 * 2);
  float* M2  = (float*)take((size_t)MP_ * 128 * 4);
  int* DEGS  = (int*)take(4ull * 40192);
  int* degf = DEGS;
  int* degb = DEGS + (40192 / 4);
  int* curf = DEGS + 2 * (40192 / 4);
  int* curb = DEGS + 3 * (40192 / 4);
  int* rpf = (int*)take((N_ + 1) * 4);
  int* rpb = (int*)take((N_ + 1) * 4);
  int* csf = (int*)take((size_t)E_ * 4);
  int* cef = (int*)take((size_t)E_ * 4);
  int* csb = (int*)take((size_t)E_ * 4);
  int* ceb = (int*)take((size_t)E_ * 4);
  float* STATS = (float*)take(256 * 4);

  // prep: weights (bf16, transposed), input cast, CSR
  hipMemsetAsync(DEGS, 0, 4ull * 40192, stream);
  k_wprep<<<2048, 256, 0, stream>>>(Wl_f, Wr_f, Wl_b, Wr_b, bl_f, br_f, bl_b, br_b,
                                    Wm1, Wm2, WCATh, BCAT, WM1h, WM2h);
  k_cast<<<(MP_ * 32 + 255) / 256, 256, 0, stream>>>(x, Xh);
  k_hist<<<(E_ + 255) / 256, 256, 0, stream>>>(fwd + E_, bwd + E_, degf, degb);
  k_scan<<<2, 256, 0, stream>>>(degf, degb, rpf, rpb);
  k_scatter<<<(E_ + 255) / 256, 256, 0, stream>>>(fwd, fwd + E_, rpf, curf, csf, cef);
  k_scatter<<<(E_ + 255) / 256, 256, 0, stream>>>(bwd, bwd + E_, rpb, curb, csb, ceb);

  for (int l = 0; l < 2; ++l) {
    const u16* hin = (l == 0) ? Xh : HBh;
    // XLXR = hin @ [Wl_f|Wr_f|Wl_b|Wr_b] + biases -> bf16 (N,2048)
    k_hgemm<128, false, true><<<dim3(16, MP_ / 128), 256, 0, stream>>>(
        hin, WCATh + (size_t)l * 2048 * 128, BCAT + l * 2048, XLXRh, nullptr, N_, 2048);
    // GAT aggregation, both directions -> FBh (N,256) = [f | b]
    k_gat<<<dim3(N_, 2), 128, 0, stream>>>(XLXRh, eattr, rpf, csf, cef, rpb, csb, ceb,
                                           We_f, We_b, att_f, att_b, bias_f, bias_b, FBh, l);
    // merge MLP (bf16 MFMA)
    k_hgemm<256, true, true><<<dim3(1, MP_ / 128), 256, 0, stream>>>(
        FBh, WM1h + (size_t)l * 128 * 256, bm1 + l * 128, M1h, nullptr, N_, 128);
    k_hgemm<128, false, false><<<dim3(1, MP_ / 128), 256, 0, stream>>>(
        M1h, WM2h + (size_t)l * 128 * 128, bm2 + l * 128, nullptr, M2, N_, 128);
    // BatchNorm (training stats) + ReLU
    hipMemsetAsync(STATS, 0, 256 * 4, stream);
    k_stats<<<64, 256, 0, stream>>>(M2, STATS);
    k_bn<<<(N_ * 32 + 255) / 256, 256, 0, stream>>>(
        M2, STATS, gamma + l * 128, beta + l * 128, HBh, (l == 1) ? (float*)d_out : nullptr);
  }
}

// Round 3
// 398.483 us; speedup vs baseline: 1.4762x; 1.2272x over previous
//
#include <hip/hip_runtime.h>

// Problem constants (match reference)
constexpr int N_  = 10000;   // nodes
constexpr int E_  = 100000;  // edges per direction
constexpr int HC_ = 512;     // H*C
constexpr int MP_ = 10112;   // N padded to multiple of 128 (79*128)
constexpr float NEG_SLOPE_ = 0.2f;

typedef unsigned int u32;
typedef unsigned short u16;
typedef __attribute__((ext_vector_type(8))) short bf16x8;
typedef __attribute__((ext_vector_type(4))) float f32x4;

__device__ __forceinline__ u16 f2bf(float f) {  // RNE
  u32 u = __float_as_uint(f);
  u32 r = u + 0x7fffu + ((u >> 16) & 1u);
  return (u16)(r >> 16);
}
__device__ __forceinline__ float bf2f(u16 u) {
  return __uint_as_float((u32)u << 16);
}
__device__ __forceinline__ void async16(const void* g, void* l) {
  // global -> LDS DMA, 16 B/lane; LDS dest = wave-uniform base + lane*16
  __builtin_amdgcn_global_load_lds((const __attribute__((address_space(1))) u32*)g,
                                   (__attribute__((address_space(3))) u32*)l, 16, 0, 0);
}

// ============================ CSR build ============================

__global__ void k_hist(const int* __restrict__ fdst, const int* __restrict__ bdst,
                       int* __restrict__ degf, int* __restrict__ degb) {
  int e = blockIdx.x * 256 + threadIdx.x;
  if (e < E_) {
    atomicAdd(&degf[fdst[e]], 1);
    atomicAdd(&degb[bdst[e]], 1);
  }
}

__global__ void k_scan(const int* __restrict__ degf, const int* __restrict__ degb,
                       int* __restrict__ rpf, int* __restrict__ rpb) {
  const int* deg = blockIdx.x ? degb : degf;
  int* rp = blockIdx.x ? rpb : rpf;
  const int CH = 40;
  int t = threadIdx.x;
  int base = t * CH;
  int s = 0;
  for (int i = 0; i < CH; ++i) {
    int idx = base + i;
    if (idx < N_) s += deg[idx];
  }
  __shared__ int lds[256];
  lds[t] = s;
  __syncthreads();
  for (int off = 1; off < 256; off <<= 1) {
    int v = (t >= off) ? lds[t - off] : 0;
    __syncthreads();
    lds[t] += v;
    __syncthreads();
  }
  int run = lds[t] - s;
  for (int i = 0; i < CH; ++i) {
    int idx = base + i;
    if (idx < N_) { rp[idx] = run; run += deg[idx]; }
  }
  if (t == 255) rp[N_] = lds[255];
}

__global__ void k_scatter(const int* __restrict__ src, const int* __restrict__ dst,
                          const int* __restrict__ rp, int* __restrict__ cur,
                          int* __restrict__ csrc, int* __restrict__ ceid) {
  int e = blockIdx.x * 256 + threadIdx.x;
  if (e < E_) {
    int d = dst[e];
    int pos = rp[d] + atomicAdd(&cur[d], 1);
    csrc[pos] = src[e];
    ceid[pos] = e;
  }
}

// ============================ param prep ============================
// WCATh[l][j][k] (bf16, j in [0,2048) = [Wl_f|Wr_f|Wl_b|Wr_b] cols, TRANSPOSED k-contig)
// BCAT [l][2048] fp32; WM1h[l][n][k] k<256; WM2h[l][n][k] k<128 (both transposed bf16)

__global__ void k_wprep(const float* __restrict__ Wl_f, const float* __restrict__ Wr_f,
                        const float* __restrict__ Wl_b, const float* __restrict__ Wr_b,
                        const float* __restrict__ bl_f, const float* __restrict__ br_f,
                        const float* __restrict__ bl_b, const float* __restrict__ br_b,
                        const float* __restrict__ Wm1, const float* __restrict__ Wm2,
                        u16* __restrict__ WCATh, float* __restrict__ BCAT,
                        u16* __restrict__ WM1h, u16* __restrict__ WM2h) {
  int idx = blockIdx.x * 256 + threadIdx.x;
  if (idx < 2 * 2048 * 128) {
    int l = idx >> 18;
    int rem = idx & 262143;
    int j = rem >> 7, k = rem & 127;
    int grp = j >> 9, jj = j & 511;
    const float* W = grp == 0 ? Wl_f : grp == 1 ? Wr_f : grp == 2 ? Wl_b : Wr_b;
    WCATh[idx] = f2bf(W[((size_t)(l * 128 + k)) * 512 + jj]);
  }
  if (idx < 2 * 2048) {
    int l = idx >> 11, j = idx & 2047;
    int grp = j >> 9, jj = j & 511;
    const float* bs = grp == 0 ? bl_f : grp == 1 ? br_f : grp == 2 ? bl_b : br_b;
    BCAT[idx] = bs[l * 512 + jj];
  }
  if (idx < 2 * 128 * 256) {  // WM1h[(l*128+n)*256+k] = Wm1[(l*256+k)*128+n]
    int l = idx >> 15;
    int rem = idx & 32767;
    int n = rem >> 8, k = rem & 255;
    WM1h[idx] = f2bf(Wm1[((size_t)(l * 256 + k)) * 128 + n]);
  }
  if (idx < 2 * 128 * 128) {  // WM2h[(l*128+n)*128+k] = Wm2[(l*128+k)*128+n]
    int l = idx >> 14;
    int rem = idx & 16383;
    int n = rem >> 7, k = rem & 127;
    WM2h[idx] = f2bf(Wm2[((size_t)(l * 128 + k)) * 128 + n]);
  }
}

__global__ void k_cast(const float* __restrict__ x, u16* __restrict__ Xh) {
  int idx = blockIdx.x * 256 + threadIdx.x;  // one thread per 4 elems
  if (idx >= MP_ * 32) return;
  int row = idx >> 5;
  int c4 = (idx & 31) << 2;
  ushort4 o;
  if (row < N_) {
    float4 v = *reinterpret_cast<const float4*>(x + (size_t)row * 128 + c4);
    o.x = f2bf(v.x); o.y = f2bf(v.y); o.z = f2bf(v.z); o.w = f2bf(v.w);
  } else {
    o.x = o.y = o.z = o.w = 0;
  }
  *reinterpret_cast<ushort4*>(Xh + (size_t)row * 128 + c4) = o;
}

// ============================ bf16 MFMA GEMM (big) ============================
// C[M, Ncols] = A[Mpad, K](bf16) @ Bt[Ncols, K]^T(bf16) + bias(fp32) -> bf16
// 128x128 tile, 4 waves (64x64 quadrant each), global_load_lds staging.

template <int K>
__global__ __launch_bounds__(256) void k_hgemm(const u16* __restrict__ A,
                                               const u16* __restrict__ Bt,
                                               const float* __restrict__ bias,
                                               u16* __restrict__ Cb, int M, int Ncols) {
  __shared__ __align__(16) u16 As[128 * 128];
  __shared__ __align__(16) u16 Bs[128 * 128];
  const int tid = threadIdx.x;
  const int lane = tid & 63, wave = tid >> 6;
  const int l16 = lane & 15, lq = lane >> 4;
  const int wm = wave & 1, wn = wave >> 1;
  const u16* Arow0 = A + (size_t)blockIdx.y * 128 * K;
  const u16* Brow0 = Bt + (size_t)blockIdx.x * 128 * K;

  f32x4 acc[4][4];
#pragma unroll
  for (int i = 0; i < 4; ++i)
#pragma unroll
    for (int j = 0; j < 4; ++j) acc[i][j] = (f32x4){0.f, 0.f, 0.f, 0.f};

  for (int kc = 0; kc < K; kc += 128) {
    if (kc) __syncthreads();
#pragma unroll
    for (int i = 0; i < 8; ++i) {
      int rg = i * 4 + wave;
      int r = rg * 4 + (lane >> 4);
      int cc = kc + (lane & 15) * 8;
      async16(Arow0 + (size_t)r * K + cc, (char*)As + rg * 1024);
      async16(Brow0 + (size_t)r * K + cc, (char*)Bs + rg * 1024);
    }
    __syncthreads();
    const u16* Ab = As + (wm * 64 + l16) * 128 + lq * 8;
    const u16* Bb = Bs + (wn * 64 + l16) * 128 + lq * 8;
#pragma unroll
    for (int ks = 0; ks < 4; ++ks) {
      bf16x8 af[4], bfr[4];
#pragma unroll
      for (int i = 0; i < 4; ++i)
        af[i] = *reinterpret_cast<const bf16x8*>(Ab + i * 16 * 128 + ks * 32);
#pragma unroll
      for (int j = 0; j < 4; ++j)
        bfr[j] = *reinterpret_cast<const bf16x8*>(Bb + j * 16 * 128 + ks * 32);
#pragma unroll
      for (int i = 0; i < 4; ++i)
#pragma unroll
        for (int j = 0; j < 4; ++j)
          acc[i][j] = __builtin_amdgcn_mfma_f32_16x16x32_bf16(af[i], bfr[j], acc[i][j], 0, 0, 0);
    }
  }

  const int row_base = blockIdx.y * 128 + wm * 64;
  const int col_base = blockIdx.x * 128 + wn * 64;
#pragma unroll
  for (int i = 0; i < 4; ++i) {
#pragma unroll
    for (int r = 0; r < 4; ++r) {
      int row = row_base + i * 16 + lq * 4 + r;
      if (row < M) {
#pragma unroll
        for (int j = 0; j < 4; ++j) {
          int col = col_base + j * 16 + l16;
          Cb[(size_t)row * Ncols + col] = f2bf(acc[i][j][r] + bias[col]);
        }
      }
    }
  }
}

// ============================ GATv2 aggregation ============================
// Block = one (node, dir). 128 threads, 4 channels each; heads = 32-lane groups.
// 2-edge unrolled loop: both gathers in flight, independent FMA/shuffle/exp chains.

__global__ __launch_bounds__(128) void k_gat(
    const u16* __restrict__ XLXRh, const float* __restrict__ eattr,
    const int* __restrict__ rpf, const int* __restrict__ csf, const int* __restrict__ cef,
    const int* __restrict__ rpb, const int* __restrict__ csb, const int* __restrict__ ceb,
    const float* __restrict__ We_f, const float* __restrict__ We_b,
    const float* __restrict__ att_f, const float* __restrict__ att_b,
    const float* __restrict__ bias_f, const float* __restrict__ bias_b,
    u16* __restrict__ FBh, int layer) {
  const int n = blockIdx.x;
  const int dir = blockIdx.y;
  const int* rp = dir ? rpb : rpf;
  const int* cs = dir ? csb : csf;
  const int* ce = dir ? ceb : cef;
  const float* We = (dir ? We_b : We_f) + layer * 16 * HC_;
  const float* att = (dir ? att_b : att_f) + layer * HC_;
  const float* bias = (dir ? bias_b : bias_f) + layer * 128;
  const int t = threadIdx.x;
  const int ch = t << 2;
  const u16* XL = XLXRh + dir * 1024;  // cols [dir*1024, +512)
  const u16* XR = XL + 512;

  float4 a4 = *reinterpret_cast<const float4*>(att + ch);
  ushort4 xru = *reinterpret_cast<const ushort4*>(XR + (size_t)n * 2048 + ch);
  float xrx = bf2f(xru.x), xry = bf2f(xru.y), xrz = bf2f(xru.z), xrw = bf2f(xru.w);
  float4 we[16];
#pragma unroll
  for (int k = 0; k < 16; ++k)
    we[k] = *reinterpret_cast<const float4*>(We + k * HC_ + ch);

  // pre-reduction per-lane partial for one edge (z -> leaky -> att-dot over 4 ch)
  auto pre = [&](float xx, float xy, float xz, float xw,
                 float4 e0, float4 e1, float4 e2, float4 e3) -> float {
    float zx = xx + xrx, zy = xy + xry, zz = xz + xrz, zw = xw + xrw;
#define EE_(c, kk)                  \
  zx = fmaf(c, we[kk].x, zx);       \
  zy = fmaf(c, we[kk].y, zy);       \
  zz = fmaf(c, we[kk].z, zz);       \
  zw = fmaf(c, we[kk].w, zw)
    EE_(e0.x, 0); EE_(e0.y, 1); EE_(e0.z, 2); EE_(e0.w, 3);
    EE_(e1.x, 4); EE_(e1.y, 5); EE_(e1.z, 6); EE_(e1.w, 7);
    EE_(e2.x, 8); EE_(e2.y, 9); EE_(e2.z, 10); EE_(e2.w, 11);
    EE_(e3.x, 12); EE_(e3.y, 13); EE_(e3.z, 14); EE_(e3.w, 15);
#undef EE_
    float lx = zx > 0.f ? zx : NEG_SLOPE_ * zx;
    float ly = zy > 0.f ? zy : NEG_SLOPE_ * zy;
    float lz = zz > 0.f ? zz : NEG_SLOPE_ * zz;
    float lw = zw > 0.f ? zw : NEG_SLOPE_ * zw;
    return fmaf(lx, a4.x, fmaf(ly, a4.y, fmaf(lz, a4.z, lw * a4.w)));
  };

  float accx = 0.f, accy = 0.f, accz = 0.f, accw = 0.f;
  float denom = 0.f;
  const int s = rp[n], epos = rp[n + 1];
  int i = s;
  for (; i + 2 <= epos; i += 2) {
    int sn0 = cs[i], sn1 = cs[i + 1];
    int ei0 = ce[i], ei1 = ce[i + 1];
    ushort4 xu0 = *reinterpret_cast<const ushort4*>(XL + (size_t)sn0 * 2048 + ch);
    ushort4 xu1 = *reinterpret_cast<const ushort4*>(XL + (size_t)sn1 * 2048 + ch);
    const float4* p0 = reinterpret_cast<const float4*>(eattr + (size_t)ei0 * 16);
    const float4* p1 = reinterpret_cast<const float4*>(eattr + (size_t)ei1 * 16);
    float4 A0 = p0[0], A1 = p0[1], A2 = p0[2], A3 = p0[3];
    float4 B0 = p1[0], B1 = p1[1], B2 = p1[2], B3 = p1[3];
    float x00 = bf2f(xu0.x), x01 = bf2f(xu0.y), x02 = bf2f(xu0.z), x03 = bf2f(xu0.w);
    float x10 = bf2f(xu1.x), x11 = bf2f(xu1.y), x12 = bf2f(xu1.z), x13 = bf2f(xu1.w);
    float pA = pre(x00, x01, x02, x03, A0, A1, A2, A3);
    float pB = pre(x10, x11, x12, x13, B0, B1, B2, B3);
    // interleaved 32-lane (per-head) reductions
#pragma unroll
    for (int kk = 1; kk < 32; kk <<= 1) {
      pA += __shfl_xor(pA, kk, 32);
      pB += __shfl_xor(pB, kk, 32);
    }
    float ex0 = __expf(pA);  // logits O(+-3): no max-subtraction needed
    float ex1 = __expf(pB);
    denom += ex0 + ex1;
    accx = fmaf(ex0, x00, fmaf(ex1, x10, accx));
    accy = fmaf(ex0, x01, fmaf(ex1, x11, accy));
    accz = fmaf(ex0, x02, fmaf(ex1, x12, accz));
    accw = fmaf(ex0, x03, fmaf(ex1, x13, accw));
  }
  if (i < epos) {
    int sn0 = cs[i], ei0 = ce[i];
    ushort4 xu0 = *reinterpret_cast<const ushort4*>(XL + (size_t)sn0 * 2048 + ch);
    const float4* p0 = reinterpret_cast<const float4*>(eattr + (size_t)ei0 * 16);
    float4 A0 = p0[0], A1 = p0[1], A2 = p0[2], A3 = p0[3];
    float x00 = bf2f(xu0.x), x01 = bf2f(xu0.y), x02 = bf2f(xu0.z), x03 = bf2f(xu0.w);
    float pA = pre(x00, x01, x02, x03, A0, A1, A2, A3);
#pragma unroll
    for (int kk = 1; kk < 32; kk <<= 1) pA += __shfl_xor(pA, kk, 32);
    float ex0 = __expf(pA);
    denom += ex0;
    accx = fmaf(ex0, x00, accx);
    accy = fmaf(ex0, x01, accy);
    accz = fmaf(ex0, x02, accz);
    accw = fmaf(ex0, x03, accw);
  }

  __shared__ __align__(16) float red[512];
  float inv = denom > 0.f ? 1.f / denom : 0.f;  // deg==0 -> out = bias
  red[ch] = accx * inv;
  red[ch + 1] = accy * inv;
  red[ch + 2] = accz * inv;
  red[ch + 3] = accw * inv;
  __syncthreads();
  if (t < 32) {  // head mean + bias -> bf16
    int c = t << 2;
    float4 r0 = *reinterpret_cast<const float4*>(&red[c]);
    float4 r1 = *reinterpret_cast<const float4*>(&red[c + 128]);
    float4 r2 = *reinterpret_cast<const float4*>(&red[c + 256]);
    float4 r3 = *reinterpret_cast<const float4*>(&red[c + 384]);
    float4 b4 = *reinterpret_cast<const float4*>(bias + c);
    ushort4 o;
    o.x = f2bf(0.25f * (r0.x + r1.x + r2.x + r3.x) + b4.x);
    o.y = f2bf(0.25f * (r0.y + r1.y + r2.y + r3.y) + b4.y);
    o.z = f2bf(0.25f * (r0.z + r1.z + r2.z + r3.z) + b4.z);
    o.w = f2bf(0.25f * (r0.w + r1.w + r2.w + r3.w) + b4.w);
    *reinterpret_cast<ushort4*>(FBh + (size_t)n * 256 + dir * 128 + c) = o;
  }
}

// ============================ fused merge MLP + BN stats ============================
// Per block: 64 node rows. GEMM1 computed TRANSPOSED (M1T[feat][node] = W1 @ FB^T)
// so C-layout r-runs are contiguous in k2 -> ds_write_b64 into M1s[m][k2].
// Then GEMM2 (M2 = M1 @ W2^T) from LDS, epilogue accumulates BN stats atomically.

__global__ __launch_bounds__(256) void k_mlp(const u16* __restrict__ FBh,
                                             const u16* __restrict__ W1,
                                             const float* __restrict__ b1,
                                             const u16* __restrict__ W2,
                                             const float* __restrict__ b2,
                                             float* __restrict__ M2,
                                             float* __restrict__ STATS) {
  __shared__ __align__(16) u16 As[128 * 128];   // W1 chunk [n][k=128], then W2 [n2][k2]
  __shared__ __align__(16) u16 Bs[64 * 128];    // FB chunk [m][k=128]
  __shared__ __align__(16) u16 M1s[64 * 128];   // M1 [m][k2=128] bf16
  __shared__ float ls[256];
  const int tid = threadIdx.x;
  const int lane = tid & 63, wave = tid >> 6;
  const int l16 = lane & 15, lq = lane >> 4;
  const int mb = blockIdx.x * 64;

  // ---- GEMM1: M1T[128 feat][64 nodes], K=256 ----
  const int wr = wave & 1, wc = wave >> 1;   // feat half / node half(32)
  f32x4 acc1[4][2];
#pragma unroll
  for (int i = 0; i < 4; ++i)
#pragma unroll
    for (int j = 0; j < 2; ++j) acc1[i][j] = (f32x4){0.f, 0.f, 0.f, 0.f};

  for (int kc = 0; kc < 256; kc += 128) {
    if (kc) __syncthreads();
#pragma unroll
    for (int tI = 0; tI < 8; ++tI) {  // W1: 128 rows x 256B
      int rg = tI * 4 + wave;
      int r = rg * 4 + (lane >> 4);
      async16(W1 + (size_t)r * 256 + kc + (lane & 15) * 8, (char*)As + rg * 1024);
    }
#pragma unroll
    for (int tI = 0; tI < 4; ++tI) {  // FB: 64 rows x 256B
      int rg = tI * 4 + wave;
      int r = rg * 4 + (lane >> 4);
      async16(FBh + (size_t)(mb + r) * 256 + kc + (lane & 15) * 8, (char*)Bs + rg * 1024);
    }
    __syncthreads();
#pragma unroll
    for (int ks = 0; ks < 4; ++ks) {
      bf16x8 af[4], bfv[2];
#pragma unroll
      for (int i = 0; i < 4; ++i)
        af[i] = *reinterpret_cast<const bf16x8*>(As + (wr * 64 + i * 16 + l16) * 128 + ks * 32 + lq * 8);
#pragma unroll
      for (int j = 0; j < 2; ++j)
        bfv[j] = *reinterpret_cast<const bf16x8*>(Bs + (wc * 32 + j * 16 + l16) * 128 + ks * 32 + lq * 8);
#pragma unroll
      for (int i = 0; i < 4; ++i)
#pragma unroll
        for (int j = 0; j < 2; ++j)
          acc1[i][j] = __builtin_amdgcn_mfma_f32_16x16x32_bf16(af[i], bfv[j], acc1[i][j], 0, 0, 0);
    }
  }
  ls[tid] = 0.f;  // zero stats partials (used after 2 barriers)
  // epilogue1: bias + relu -> bf16 -> M1s[m][k2] (r-run contiguous in k2)
#pragma unroll
  for (int i = 0; i < 4; ++i) {
    float4 b1v = *reinterpret_cast<const float4*>(b1 + wr * 64 + i * 16 + lq * 4);
    float bb[4] = {b1v.x, b1v.y, b1v.z, b1v.w};
#pragma unroll
    for (int j = 0; j < 2; ++j) {
      int m = wc * 32 + j * 16 + l16;
      int k2 = wr * 64 + i * 16 + lq * 4;
      ushort4 o;
      o.x = f2bf(fmaxf(acc1[i][j][0] + bb[0], 0.f));
      o.y = f2bf(fmaxf(acc1[i][j][1] + bb[1], 0.f));
      o.z = f2bf(fmaxf(acc1[i][j][2] + bb[2], 0.f));
      o.w = f2bf(fmaxf(acc1[i][j][3] + bb[3], 0.f));
      *reinterpret_cast<ushort4*>(M1s + m * 128 + k2) = o;
    }
  }
  __syncthreads();  // M1s visible; As free for W2
#pragma unroll
  for (int tI = 0; tI < 8; ++tI) {  // W2: 128 rows x 256B
    int rg = tI * 4 + wave;
    int r = rg * 4 + (lane >> 4);
    async16(W2 + (size_t)r * 128 + (lane & 15) * 8, (char*)As + rg * 1024);
  }
  __syncthreads();

  // ---- GEMM2: M2[64 nodes][128 feat], K=128 ----
  const int wr2 = wave & 1, wc2 = wave >> 1;  // node half(32) / feat half(64)
  f32x4 acc2[2][4];
#pragma unroll
  for (int i = 0; i < 2; ++i)
#pragma unroll
    for (int j = 0; j < 4; ++j) acc2[i][j] = (f32x4){0.f, 0.f, 0.f, 0.f};
#pragma unroll
  for (int ks = 0; ks < 4; ++ks) {
    bf16x8 af2[2], bf2v[4];
#pragma unroll
    for (int i = 0; i < 2; ++i)
      af2[i] = *reinterpret_cast<const bf16x8*>(M1s + (wr2 * 32 + i * 16 + l16) * 128 + ks * 32 + lq * 8);
#pragma unroll
    for (int j = 0; j < 4; ++j)
      bf2v[j] = *reinterpret_cast<const bf16x8*>(As + (wc2 * 64 + j * 16 + l16) * 128 + ks * 32 + lq * 8);
#pragma unroll
    for (int i = 0; i < 2; ++i)
#pragma unroll
      for (int j = 0; j < 4; ++j)
        acc2[i][j] = __builtin_amdgcn_mfma_f32_16x16x32_bf16(af2[i], bf2v[j], acc2[i][j], 0, 0, 0);
  }

  // epilogue2: bias, store M2 (valid rows), BN stats partials
  float s1[4] = {0.f, 0.f, 0.f, 0.f}, s2[4] = {0.f, 0.f, 0.f, 0.f};
  float b2j[4];
#pragma unroll
  for (int j = 0; j < 4; ++j) b2j[j] = b2[wc2 * 64 + j * 16 + l16];
#pragma unroll
  for (int i = 0; i < 2; ++i) {
#pragma unroll
    for (int r = 0; r < 4; ++r) {
      int m = mb + wr2 * 32 + i * 16 + lq * 4 + r;
      if (m < N_) {
#pragma unroll
        for (int j = 0; j < 4; ++j) {
          float v = acc2[i][j][r] + b2j[j];
          M2[(size_t)m * 128 + wc2 * 64 + j * 16 + l16] = v;
          s1[j] += v;
          s2[j] = fmaf(v, v, s2[j]);
        }
      }
    }
  }
#pragma unroll
  for (int j = 0; j < 4; ++j) {
    int c = wc2 * 64 + j * 16 + l16;
    atomicAdd(&ls[c], s1[j]);
    atomicAdd(&ls[128 + c], s2[j]);
  }
  __syncthreads();
  if (tid < 128) {
    atomicAdd(&STATS[tid], ls[tid]);
    atomicAdd(&STATS[128 + tid], ls[128 + tid]);
  }
}

// ============================ BatchNorm finalize ============================

__global__ void k_bn(const float* __restrict__ m2, const float* __restrict__ stats,
                     const float* __restrict__ gamma, const float* __restrict__ beta,
                     u16* __restrict__ houth, float* __restrict__ outf) {
  int idx = blockIdx.x * 256 + threadIdx.x;
  if (idx >= N_ * 32) return;
  int n = idx >> 5;
  int c = (idx & 31) << 2;
  float4 v = *reinterpret_cast<const float4*>(m2 + (size_t)n * 128 + c);
  const float invN = 1.f / (float)N_;
  float o[4];
  float vv[4] = {v.x, v.y, v.z, v.w};
#pragma unroll
  for (int q = 0; q < 4; ++q) {
    float mu = stats[c + q] * invN;
    float var = stats[128 + c + q] * invN - mu * mu;
    float rs = rsqrtf(var + 1e-5f);
    o[q] = fmaxf(gamma[c + q] * (vv[q] - mu) * rs + beta[c + q], 0.f);
  }
  ushort4 oh;
  oh.x = f2bf(o[0]); oh.y = f2bf(o[1]); oh.z = f2bf(o[2]); oh.w = f2bf(o[3]);
  *reinterpret_cast<ushort4*>(houth + (size_t)n * 128 + c) = oh;
  if (outf) {
    float4 of = make_float4(o[0], o[1], o[2], o[3]);
    *reinterpret_cast<float4*>(outf + (size_t)n * 128 + c) = of;
  }
}

// ============================ launch ============================

extern "C" void kernel_launch(void* const* d_in, const int* in_sizes, int n_in,
                              void* d_out, int out_size, void* d_ws, size_t ws_size,
                              hipStream_t stream) {
  (void)in_sizes; (void)n_in; (void)out_size; (void)ws_size;
  const float* x      = (const float*)d_in[0];
  const int*   fwd    = (const int*)d_in[1];
  const int*   bwd    = (const int*)d_in[2];
  const float* eattr  = (const float*)d_in[3];
  const float* Wl_f   = (const float*)d_in[4];
  const float* bl_f   = (const float*)d_in[5];
  const float* Wr_f   = (const float*)d_in[6];
  const float* br_f   = (const float*)d_in[7];
  const float* We_f   = (const float*)d_in[8];
  const float* att_f  = (const float*)d_in[9];
  const float* bias_f = (const float*)d_in[10];
  const float* Wl_b   = (const float*)d_in[11];
  const float* bl_b   = (const float*)d_in[12];
  const float* Wr_b   = (const float*)d_in[13];
  const float* br_b   = (const float*)d_in[14];
  const float* We_b   = (const float*)d_in[15];
  const float* att_b  = (const float*)d_in[16];
  const float* bias_b = (const float*)d_in[17];
  const float* Wm1    = (const float*)d_in[18];
  const float* bm1    = (const float*)d_in[19];
  const float* Wm2    = (const float*)d_in[20];
  const float* bm2    = (const float*)d_in[21];
  const float* gamma  = (const float*)d_in[22];
  const float* beta   = (const float*)d_in[23];

  char* ws = (char*)d_ws;
  size_t off = 0;
  auto take = [&](size_t bytes) -> char* {
    char* p = ws + off;
    off += (bytes + 255) & ~(size_t)255;
    return p;
  };
  u16* WCATh = (u16*)take(2ull * 2048 * 128 * 2);
  float* BCAT = (float*)take(2ull * 2048 * 4);
  u16* WM1h = (u16*)take(2ull * 128 * 256 * 2);
  u16* WM2h = (u16*)take(2ull * 128 * 128 * 2);
  u16* Xh    = (u16*)take((size_t)MP_ * 128 * 2);
  u16* HBh   = (u16*)take((size_t)MP_ * 128 * 2);
  u16* XLXRh = (u16*)take((size_t)MP_ * 2048 * 2);
  u16* FBh   = (u16*)take((size_t)MP_ * 256 * 2);
  float* M2  = (float*)take((size_t)MP_ * 128 * 4);
  int* DEGS  = (int*)take(4ull * 40192);
  int* degf = DEGS;
  int* degb = DEGS + (40192 / 4);
  int* curf = DEGS + 2 * (40192 / 4);
  int* curb = DEGS + 3 * (40192 / 4);
  int* rpf = (int*)take((N_ + 1) * 4);
  int* rpb = (int*)take((N_ + 1) * 4);
  int* csf = (int*)take((size_t)E_ * 4);
  int* cef = (int*)take((size_t)E_ * 4);
  int* csb = (int*)take((size_t)E_ * 4);
  int* ceb = (int*)take((size_t)E_ * 4);
  float* STATS = (float*)take(256 * 4);

  // prep: weights (bf16, transposed), input cast, CSR
  hipMemsetAsync(DEGS, 0, 4ull * 40192, stream);
  k_wprep<<<2048, 256, 0, stream>>>(Wl_f, Wr_f, Wl_b, Wr_b, bl_f, br_f, bl_b, br_b,
                                    Wm1, Wm2, WCATh, BCAT, WM1h, WM2h);
  k_cast<<<(MP_ * 32 + 255) / 256, 256, 0, stream>>>(x, Xh);
  k_hist<<<(E_ + 255) / 256, 256, 0, stream>>>(fwd + E_, bwd + E_, degf, degb);
  k_scan<<<2, 256, 0, stream>>>(degf, degb, rpf, rpb);
  k_scatter<<<(E_ + 255) / 256, 256, 0, stream>>>(fwd, fwd + E_, rpf, curf, csf, cef);
  k_scatter<<<(E_ + 255) / 256, 256, 0, stream>>>(bwd, bwd + E_, rpb, curb, csb, ceb);

  for (int l = 0; l < 2; ++l) {
    const u16* hin = (l == 0) ? Xh : HBh;
    // XLXR = hin @ [Wl_f|Wr_f|Wl_b|Wr_b] + biases -> bf16 (N,2048)
    k_hgemm<128><<<dim3(16, MP_ / 128), 256, 0, stream>>>(
        hin, WCATh + (size_t)l * 2048 * 128, BCAT + l * 2048, XLXRh, N_, 2048);
    // GAT aggregation, both directions -> FBh (N,256) = [f | b]
    k_gat<<<dim3(N_, 2), 128, 0, stream>>>(XLXRh, eattr, rpf, csf, cef, rpb, csb, ceb,
                                           We_f, We_b, att_f, att_b, bias_f, bias_b, FBh, l);
    // fused merge MLP + BN stats
    hipMemsetAsync(STATS, 0, 256 * 4, stream);
    k_mlp<<<MP_ / 64, 256, 0, stream>>>(FBh, WM1h + (size_t)l * 128 * 256, bm1 + l * 128,
                                        WM2h + (size_t)l * 128 * 128, bm2 + l * 128, M2, STATS);
    // BN finalize + ReLU
    k_bn<<<(N_ * 32 + 255) / 256, 256, 0, stream>>>(
        M2, STATS, gamma + l * 128, beta + l * 128, HBh, (l == 1) ? (float*)d_out : nullptr);
  }
}